// Round 12
// baseline (134.791 us; speedup 1.0000x reference)
//
#include <hip/hip_runtime.h>

typedef unsigned long long ull;

#define NANCH   131072
#define NMAX    64
#define NBATCH  16
#define THREADS 256

// ---------------------------------------------------------------------------
// ws layout (bytes):
//   0        ull cells[1024]        packed per-(batch,gt) argmax
//   8192     double partials[768]
//   14336    int cst[256]           cell start offsets
//   16384    int CH[256cells][256chunks]  (cell-major!)
//   278528   int cellid[NANCH]
//   802816   float4 sorted[NANCH]
//   2899968  int sidx[NANCH]        (= 3424256 total, proven available in R11)
// cells packed as (r_bits<<32)|(0x7FFFFFFF-idx), r = inter/(areaA+areaB),
// monotone bijection of iou, >= 0 -> float bits unsigned-monotonic; ties ->
// larger low word -> smaller ORIGINAL anchor index == JAX argmax semantics.
// Init 0x7FFFFFFF == pack(0, idx 0): no-overlap gt -> argmax 0, matching JAX.
// ---------------------------------------------------------------------------
#define OFF_PART  8192
#define OFF_CST   14336
#define OFF_CH    16384
#define OFF_CID   278528
#define OFF_SRT   802816
#define OFF_SIX   2899968

#define NB_A   256                   // role A blocks: 64 sblk x 4 bg
#define NB_B   512                   // role B blocks
#define GRID_M 768                   // 1:2 interleave via bid%3

__device__ __forceinline__ float focal_f(float p) {
    float om = 1.0f - p;
    return -om * om * __logf(p);
}

// ========================= sort stage =========================
__global__ __launch_bounds__(256) void k_hist(
    const float* __restrict__ anchors, int* __restrict__ cellid,
    int* __restrict__ CH)
{
    __shared__ int h[256];
    int tid = threadIdx.x, c = blockIdx.x;
    h[tid] = 0; __syncthreads();
    #pragma unroll
    for (int k = 0; k < 2; ++k) {
        int i = c*512 + tid + k*256;
        float4 v = reinterpret_cast<const float4*>(anchors)[i];
        int cx = (int)(v.x * 20.0f); cx = cx < 0 ? 0 : (cx > 15 ? 15 : cx);
        int cy = (int)(v.y * 20.0f); cy = cy < 0 ? 0 : (cy > 15 ? 15 : cy);
        int cell = cy*16 + cx;
        cellid[i] = cell;
        atomicAdd(&h[cell], 1);
    }
    __syncthreads();
    CH[tid*256 + c] = h[tid];        // cell-major: row per cell
}

__global__ __launch_bounds__(256) void k_scan(
    int* __restrict__ CH, int* __restrict__ cst, ull* __restrict__ cells)
{
    __shared__ int tot[256];
    __shared__ int cs[256];
    int b = threadIdx.x;
    int* row = CH + b*256;           // contiguous per thread
    int run = 0;
    for (int c = 0; c < 256; c += 16) {
        int v[16];
        #pragma unroll
        for (int i = 0; i < 16; ++i) v[i] = row[c+i];      // 16 loads in flight
        #pragma unroll
        for (int i = 0; i < 16; ++i) { row[c+i] = run; run += v[i]; }
    }
    tot[b] = run;
    __syncthreads();
    if (b == 0) { int s = 0; for (int i = 0; i < 256; ++i) { cs[i] = s; s += tot[i]; } }
    __syncthreads();
    cst[b] = cs[b];
    for (int i = b; i < NBATCH*NMAX; i += 256) cells[i] = 0x7FFFFFFFull;
}

__global__ __launch_bounds__(256) void k_scatter(
    const float* __restrict__ anchors, const int* __restrict__ cellid,
    const int* __restrict__ CH, const int* __restrict__ cst,
    float4* __restrict__ sorted, int* __restrict__ sidx)
{
    __shared__ int lcc[512];
    int tid = threadIdx.x, c = blockIdx.x;
    lcc[tid]     = cellid[c*512 + tid];
    lcc[tid+256] = cellid[c*512 + 256 + tid];
    __syncthreads();
    int i0 = 2*tid, i1 = 2*tid + 1;
    int c0 = lcc[i0], c1 = lcc[i1];
    int r0 = 0, r1 = 0;
    for (int j = 0; j < i0; ++j) { int cj = lcc[j]; r0 += (cj==c0)?1:0; r1 += (cj==c1)?1:0; }
    r1 += (c0 == c1) ? 1 : 0;
    int g0 = c*512 + i0, g1 = c*512 + i1;
    int p0 = CH[c0*256 + c] + cst[c0] + r0;
    int p1 = CH[c1*256 + c] + cst[c1] + r1;
    sorted[p0] = reinterpret_cast<const float4*>(anchors)[g0]; sidx[p0] = g0;
    sorted[p1] = reinterpret_cast<const float4*>(anchors)[g1]; sidx[p1] = g1;
}

// ========================= fused main =========================
// bid%3==0 -> role A: wave owns 512 contiguous sorted anchors (8/lane).
//   Per batch: 64 lanes test 64 gts vs wave bbox -> ONE ballot mask; iterate
//   set bits only. Survivors processed in PAIRS (2 interleaved butterflies),
//   merged into per-block LDS cells; one global atomic per (block,gt) at end.
//   Positives (cnt>0) add fg*(1+10c) - bg focal deltas (sparse gathers).
// else -> role B: coalesced streaming background focal over all classes.
__global__ __launch_bounds__(THREADS) void k_main_s(
    const float* __restrict__ thr_p,
    const float* __restrict__ classes,
    const float4* __restrict__ sorted,
    const int*   __restrict__ sidx,
    const float* __restrict__ gt,
    const int*   __restrict__ nobj,
    ull* __restrict__ cells,
    double* __restrict__ partials)
{
    int bid = blockIdx.x, tid = threadIdx.x;
    int wv = tid >> 6, ln = tid & 63;
    float thr = *thr_p;
    float q   = thr / (1.0f + thr);  // iou>thr <=> inter > q*aarea + q*garea
    __shared__ double sw[4];
    double acc = 0.0;

    if (bid % 3 == 0) {
        // ---------------- role A ----------------
        int aid  = bid / 3;          // 0..255
        int sblk = aid >> 2, bg = aid & 3;
        __shared__ float4 sgt[4*NMAX];
        __shared__ float2 sgq[4*NMAX];   // {q*garea, garea}
        __shared__ int    snobj[4];
        __shared__ ull    lc[4*NMAX];
        {
            int bb = tid >> 6, n = tid & 63;
            int b = bg + 4*bb;
            float4 g = reinterpret_cast<const float4*>(gt)[b*NMAX + n];
            float x2 = g.x + g.z, y2 = g.y + g.w;
            sgt[tid] = make_float4(g.x, g.y, x2, y2);
            float gar = (x2 - g.x) * (y2 - g.y);
            sgq[tid] = make_float2(q * gar, gar);
            lc[tid] = 0ull;
            if (n == 0) snobj[bb] = nobj[b];
        }
        __syncthreads();

        int abase = sblk*2048 + wv*512;
        float4 A[8]; float aar[8], qa[8]; int orig[8];
        float bx1 = 1e30f, by1 = 1e30f, bx2 = -1e30f, by2 = -1e30f;
        #pragma unroll
        for (int k = 0; k < 8; ++k) {
            int s = abase + k*64 + ln;
            A[k] = sorted[s]; orig[k] = sidx[s];
            aar[k] = (A[k].z - A[k].x) * (A[k].w - A[k].y);
            qa[k]  = q * aar[k];
            bx1 = fminf(bx1, A[k].x); by1 = fminf(by1, A[k].y);
            bx2 = fmaxf(bx2, A[k].z); by2 = fmaxf(by2, A[k].w);
        }
        #pragma unroll
        for (int off = 32; off; off >>= 1) {
            bx1 = fminf(bx1, __shfl_xor(bx1, off, 64));
            by1 = fminf(by1, __shfl_xor(by1, off, 64));
            bx2 = fmaxf(bx2, __shfl_xor(bx2, off, 64));
            by2 = fmaxf(by2, __shfl_xor(by2, off, 64));
        }

        const float2* cls2 = reinterpret_cast<const float2*>(classes);
        for (int bb = 0; bb < 4; ++bb) {
            int b = bg + 4*bb, no = snobj[bb], base = bb*NMAX;
            // vectorized skip test: lane ln evaluates gt ln -> one ballot
            float4 gl = sgt[base + ln];
            bool ov = (ln < no) && (gl.x < bx2) && (gl.z > bx1)
                                && (gl.y < by2) && (gl.w > by1);
            ull mask = __ballot(ov);
            int cnt[8];
            #pragma unroll
            for (int k = 0; k < 8; ++k) cnt[k] = 0;

            while (mask) {               // survivors only; pairs for ILP
                int n0 = __ffsll(mask) - 1; mask &= mask - 1;
                int n1 = -1;
                if (mask) { n1 = __ffsll(mask) - 1; mask &= mask - 1; }
                bool h1 = n1 >= 0;
                float4 gA = sgt[base + n0]; float2 qA = sgq[base + n0];
                float4 gB = gA;            float2 qB = qA;
                if (h1) { gB = sgt[base + n1]; qB = sgq[base + n1]; }
                ull pkA = 0, pkB = 0;
                #pragma unroll
                for (int k = 0; k < 8; ++k) {
                    {
                        float lx = fmaxf(A[k].x, gA.x), ly = fmaxf(A[k].y, gA.y);
                        float rx = fminf(A[k].z, gA.z), ry = fminf(A[k].w, gA.w);
                        float w = fmaxf(rx-lx, 0.f), h = fmaxf(ry-ly, 0.f);
                        float inter = w * h;
                        cnt[k] += (inter > qa[k] + qA.x) ? 1 : 0;
                        float r = inter * __builtin_amdgcn_rcpf(aar[k] + qA.y);
                        ull pk = ((ull)__float_as_uint(r) << 32)
                               | (ull)(0x7FFFFFFFu - (unsigned)orig[k]);
                        pkA = pk > pkA ? pk : pkA;
                    }
                    if (h1) {
                        float lx = fmaxf(A[k].x, gB.x), ly = fmaxf(A[k].y, gB.y);
                        float rx = fminf(A[k].z, gB.z), ry = fminf(A[k].w, gB.w);
                        float w = fmaxf(rx-lx, 0.f), h = fmaxf(ry-ly, 0.f);
                        float inter = w * h;
                        cnt[k] += (inter > qa[k] + qB.x) ? 1 : 0;
                        float r = inter * __builtin_amdgcn_rcpf(aar[k] + qB.y);
                        ull pk = ((ull)__float_as_uint(r) << 32)
                               | (ull)(0x7FFFFFFFu - (unsigned)orig[k]);
                        pkB = pk > pkB ? pk : pkB;
                    }
                }
                #pragma unroll
                for (int off = 32; off; off >>= 1) {   // 2 interleaved chains
                    ull o = __shfl_xor(pkA, off, 64); pkA = o > pkA ? o : pkA;
                    if (h1) { ull o2 = __shfl_xor(pkB, off, 64); pkB = o2 > pkB ? o2 : pkB; }
                }
                if (ln == 0) {
                    atomicMax(&lc[base + n0], pkA);    // LDS atomic (cheap)
                    if (h1) atomicMax(&lc[base + n1], pkB);
                }
            }
            // positives epilogue (sparse gathers)
            #pragma unroll
            for (int k = 0; k < 8; ++k) {
                if (cnt[k] > 0) {
                    float2 cc = cls2[(size_t)b * NANCH + orig[k]];
                    acc += (double)(focal_f(cc.y) * (1.0f + 10.0f * (float)cnt[k]))
                         - (double)focal_f(cc.x);
                }
            }
        }
        __syncthreads();
        {   // one global atomic per (block,gt) with any candidate
            ull v = lc[tid];
            if (v) {
                int bb = tid >> 6, n = tid & 63;
                atomicMax(&cells[(bg + 4*bb)*NMAX + n], v);
            }
        }
    } else {
        // ---------------- role B: background focal stream ----------------
        int rid = (bid / 3) * 2 + (bid % 3) - 1;       // 0..511
        const float4* c4 = reinterpret_cast<const float4*>(classes);
        size_t basec = (size_t)rid * 2048 + tid;
        #pragma unroll
        for (int it = 0; it < 8; ++it) {
            float4 v = c4[basec + (size_t)it * 256];
            acc += (double)focal_f(v.x) + (double)focal_f(v.z);
        }
    }

    #pragma unroll
    for (int off = 32; off; off >>= 1) acc += __shfl_xor(acc, off, 64);
    if (ln == 0) sw[wv] = acc;
    __syncthreads();
    if (tid == 0) partials[bid] = sw[0] + sw[1] + sw[2] + sw[3];
}

// ======================= tail (correction + reduce) ========================
__global__ __launch_bounds__(1024) void k_tail(
    const float* __restrict__ thr_p, const float* __restrict__ classes,
    const float* __restrict__ anchors, const float* __restrict__ gt,
    const int* __restrict__ nobj, const ull* __restrict__ cells,
    const double* __restrict__ partials, float* __restrict__ out)
{
    int tid = threadIdx.x;
    int b = tid >> 6, n = tid & 63;
    float thr = *thr_p;
    float q   = thr / (1.0f + thr);

    __shared__ float4 sbox[NBATCH*NMAX];
    __shared__ float  sqg[NBATCH*NMAX];
    __shared__ int    sidxs[NBATCH*NMAX];
    __shared__ double sdelta[NBATCH];
    __shared__ double sw[16];

    int n_obj = nobj[b];
    {
        float4 g = reinterpret_cast<const float4*>(gt)[b*NMAX + n];
        float x2 = g.x + g.z, y2 = g.y + g.w;
        sbox[tid] = make_float4(g.x, g.y, x2, y2);
        float gar = (x2 - g.x) * (y2 - g.y);
        sqg[tid]  = q * gar;
    }
    __syncthreads();

    int bi = -1; bool need = false;
    float4 av = make_float4(0.f,0.f,0.f,0.f);
    float qa = 0.f;
    if (n < n_obj) {
        ull pkv = cells[tid];
        bi = (int)(0x7FFFFFFFu - (unsigned)(pkv & 0xFFFFFFFFull));
        av = reinterpret_cast<const float4*>(anchors)[bi];
        float aar = (av.z - av.x) * (av.w - av.y);
        qa = q * aar;
        float4 g = sbox[tid];
        float lx = fmaxf(av.x, g.x), ly = fmaxf(av.y, g.y);
        float rx = fminf(av.z, g.z), ry = fminf(av.w, g.w);
        float w = fmaxf(rx - lx, 0.f), h = fmaxf(ry - ly, 0.f);
        float inter = w * h;
        need = !(inter > qa + sqg[tid]);  // forced adds a bit only if !pos
    }
    sidxs[tid] = need ? bi : -1;
    __syncthreads();

    double delta = 0.0;
    if (need) {
        bool first = true; int extra = 0;
        int base = b * NMAX;
        for (int m = 0; m < NMAX; ++m) {
            if (sidxs[base + m] == bi) { if (m < n) first = false; ++extra; }
        }
        if (first) {
            int count = 0;
            for (int m = 0; m < n_obj; ++m) {
                float4 g = sbox[base + m];
                float lx = fmaxf(av.x, g.x), ly = fmaxf(av.y, g.y);
                float rx = fminf(av.z, g.z), ry = fminf(av.w, g.w);
                float w = fmaxf(rx - lx, 0.f), h = fmaxf(ry - ly, 0.f);
                float inter = w * h;
                count += (inter > qa + sqg[base + m]) ? 1 : 0;
            }
            float2 c = reinterpret_cast<const float2*>(classes)[(size_t)b * NANCH + bi];
            float po = (count > 0) ? c.y : c.x;
            float fo = focal_f(po);
            float oldc = fo * (1.0f + 10.0f * (float)count);
            int cn = count + extra;
            float pn = (cn > 0) ? c.y : c.x;
            float fn = focal_f(pn);
            float newc = fn * (1.0f + 10.0f * (float)cn);
            delta = (double)newc - (double)oldc;
        }
    }
    #pragma unroll
    for (int off = 32; off; off >>= 1) delta += __shfl_xor(delta, off, 64);
    if (n == 0) sdelta[b] = delta;
    __syncthreads();

    double v = (tid < GRID_M) ? partials[tid] : 0.0;
    if (tid < NBATCH) v += sdelta[tid];
    #pragma unroll
    for (int off = 32; off; off >>= 1) v += __shfl_xor(v, off, 64);
    if ((tid & 63) == 0) sw[tid >> 6] = v;
    __syncthreads();
    if (tid == 0) {
        double tot = 0.0;
        #pragma unroll
        for (int i = 0; i < 16; ++i) tot += sw[i];
        double cls = tot * (0.01 / 16.0);
        out[0] = (float)cls;
        out[1] = (float)cls;
        out[2] = 0.0f;
    }
}

extern "C" void kernel_launch(void* const* d_in, const int* in_sizes, int n_in,
                              void* d_out, int out_size, void* d_ws, size_t ws_size,
                              hipStream_t stream) {
    const float* thr     = (const float*)d_in[0];
    const float* classes = (const float*)d_in[1];
    const float* anchors = (const float*)d_in[2];
    const float* gt      = (const float*)d_in[3];
    const int*   nobj    = (const int*)d_in[4];
    float* out = (float*)d_out;

    char* ws = (char*)d_ws;
    ull*    cells    = (ull*)(ws + 0);
    double* partials = (double*)(ws + OFF_PART);
    int*    cst      = (int*)(ws + OFF_CST);
    int*    CH       = (int*)(ws + OFF_CH);
    int*    cellid   = (int*)(ws + OFF_CID);
    float4* sorted   = (float4*)(ws + OFF_SRT);
    int*    sidx     = (int*)(ws + OFF_SIX);

    k_hist<<<256, 256, 0, stream>>>(anchors, cellid, CH);
    k_scan<<<1, 256, 0, stream>>>(CH, cst, cells);
    k_scatter<<<256, 256, 0, stream>>>(anchors, cellid, CH, cst, sorted, sidx);
    k_main_s<<<GRID_M, THREADS, 0, stream>>>(thr, classes, sorted, sidx,
                                             gt, nobj, cells, partials);
    k_tail<<<1, 1024, 0, stream>>>(thr, classes, anchors, gt, nobj, cells, partials, out);
}

// Round 13
// 95.531 us; speedup vs baseline: 1.4110x; 1.4110x over previous
//
#include <hip/hip_runtime.h>

typedef unsigned long long ull;

#define NANCH    131072
#define NMAX     64
#define NBATCH   16
#define THREADS  256
#define APT      4                       // count role: anchors per thread
#define ACH      (THREADS*APT)           // 1024 anchors per count block
#define NPAIR    8
#define NB_CNT   ((NANCH/ACH)*NPAIR)     // 1024 count blocks
#define AC_ANCH  256                     // argmax role: anchors per wave-chunk
#define BPB_A    128                     // blocks per bundle (4 waves each)
#define MAXB     16
#define NB_ARG   (MAXB*BPB_A)            // 2048 argmax blocks
#define GRID_MAIN (NB_CNT+NB_ARG)        // 3072 = 1024*3 (1:2 interleave)

// ---------------------------------------------------------------------------
// ws layout (bytes):
//   0      : ull cells[1024]       per-(batch,gt) packed argmax
//   8192   : int pairs[16]         batch pairing for count-role balance
//   8256   : int lanepk[16*64]     bundle lane -> (batch<<8)|gt, -1 invalid
//   12352  : int nbund
//   12416  : double partials[1024]
// cells packed as (r_bits<<32)|(0x7FFFFFFF-idx), r = inter/(areaA+areaB) --
// monotone bijection of iou, >= 0, so float bits are unsigned-monotonic;
// ties -> larger low word -> smaller anchor index == JAX argmax
// first-occurrence semantics.
// ---------------------------------------------------------------------------

__device__ __forceinline__ float focal_f(float p) {
    float om = 1.0f - p;
    return -om * om * __logf(p);
}

// Lean setup: FFD plan on t0 (tiny), lanepk written COOPERATIVELY (16
// wave-stores, not 520 serial ones -- this was ~15us of R10's overhead).
__global__ __launch_bounds__(64) void k_setup(
    const int* __restrict__ nobj, ull* __restrict__ cells,
    int* __restrict__ pairs, int* __restrict__ lanepk, int* __restrict__ nbund)
{
    int tid = threadIdx.x;
    for (int i = tid; i < NBATCH*NMAX; i += 64) cells[i] = 0ull;
    for (int i = tid; i < MAXB*NMAX; i += 64) lanepk[i] = -1;

    __shared__ int s_b[NBATCH], s_no[NBATCH], s_bu[NBATCH], s_st[NBATCH];
    if (tid == 0) {
        // sort batches desc by n_obj (stable)
        int ord[NBATCH], key[NBATCH];
        for (int i = 0; i < NBATCH; ++i) { ord[i] = i; key[i] = nobj[i]; }
        for (int i = 1; i < NBATCH; ++i) {
            int k = key[i], o = ord[i], j = i-1;
            while (j >= 0 && key[j] < k) { key[j+1]=key[j]; ord[j+1]=ord[j]; --j; }
            key[j+1] = k; ord[j+1] = o;
        }
        // count-role pairing: big + small -> near-equal sums
        for (int p = 0; p < NPAIR; ++p) {
            pairs[2*p]   = ord[p];
            pairs[2*p+1] = ord[NBATCH-1-p];
        }
        // argmax-role: first-fit-decreasing plan into 64-lane bundles
        int rem[MAXB]; int nb = 0;
        for (int i = 0; i < NBATCH; ++i) {
            int n = key[i], f = -1;
            for (int x = 0; x < nb; ++x) if (rem[x] >= n) { f = x; break; }
            if (f < 0) { f = nb++; rem[f] = NMAX; }
            s_b[i] = ord[i]; s_no[i] = n; s_bu[i] = f; s_st[i] = NMAX - rem[f];
            rem[f] -= n;
        }
        *nbund = nb;
    }
    __syncthreads();
    #pragma unroll
    for (int i = 0; i < NBATCH; ++i) {           // cooperative lanepk fill
        if (tid < s_no[i])
            lanepk[s_bu[i]*NMAX + s_st[i] + tid] = (s_b[i] << 8) | tid;
    }
}

// Two roles, 1:2 interleaved in dispatch order (proportional resident mix).
//  - count role: anchor-per-lane, gts from LDS, 12-op inner, NO reductions.
//  - argmax role: (batch,gt)-per-lane via bundles, 8 independent chains,
//    register DOUBLE-BUFFERED anchor loads (L2 latency hidden under compute),
//    one atomicMax per lane at the end.
__global__ __launch_bounds__(THREADS) void k_main(
    const float* __restrict__ thr_p,
    const float* __restrict__ classes,   // [B,A,2]
    const float* __restrict__ anchors,   // [A,4] xyxy
    const float* __restrict__ gt,        // [B,NMAX,4] xywh
    const int*   __restrict__ nobj,
    const int*   __restrict__ pairs,
    const int*   __restrict__ lanepk,
    const int*   __restrict__ nbund,
    ull* __restrict__ cells,
    double* __restrict__ partials)
{
    int bid0 = blockIdx.x;
    int tid  = threadIdx.x;
    float thr = *thr_p;
    float q   = thr / (1.0f + thr);      // iou>thr <=> inter > q*aarea + q*garea
    bool is_cnt = (bid0 % 3) == 0;
    int  bid    = is_cnt ? (bid0 / 3) : ((bid0 / 3) * 2 + (bid0 % 3) - 1);

    if (is_cnt) {
        // ==================== count + focal role ====================
        int chunk = bid >> 3, pr = bid & 7;
        int b0 = pairs[2*pr], b1 = pairs[2*pr+1];
        int no0 = nobj[b0], no1 = nobj[b1];

        __shared__ float4 sbox[2*NMAX];  // xyxy (degenerate-padded)
        __shared__ float  sqg[2*NMAX];   // q*garea (+inf for pads)
        __shared__ double sw[4];
        if (tid < 2*NMAX) {
            int s = tid >> 6, n = tid & 63;
            int b  = s ? b1 : b0;
            int no = s ? no1 : no0;
            float4 g = reinterpret_cast<const float4*>(gt)[b*NMAX + n];
            float x2 = g.x + g.z, y2 = g.y + g.w;
            float4 box = make_float4(g.x, g.y, x2, y2);
            float  qg  = q * ((x2 - g.x) * (y2 - g.y));
            if (n >= no) { box = make_float4(4.f,4.f,4.f,4.f); qg = __builtin_inff(); }
            sbox[tid] = box; sqg[tid] = qg;
        }
        __syncthreads();

        float ax1[APT], ay1[APT], ax2[APT], ay2[APT], qa[APT];
        int abase = chunk * ACH + tid;
        #pragma unroll
        for (int k = 0; k < APT; ++k) {
            float4 v = reinterpret_cast<const float4*>(anchors)[abase + k*THREADS];
            ax1[k]=v.x; ay1[k]=v.y; ax2[k]=v.z; ay2[k]=v.w;
            qa[k] = q * ((v.z - v.x) * (v.w - v.y));
        }

        int wv = tid >> 6, ln = tid & 63;
        double acc = 0.0;
        #pragma unroll
        for (int s = 0; s < 2; ++s) {
            int b    = s ? b1 : b0;
            int no   = s ? no1 : no0;
            int no4  = (no + 3) & ~3;
            int base = s * NMAX;
            int cnt[APT];
            #pragma unroll
            for (int k = 0; k < APT; ++k) cnt[k] = 0;

            for (int n = 0; n < no4; n += 4) {
                #pragma unroll
                for (int u = 0; u < 4; ++u) {
                    float4 g  = sbox[base + n + u];
                    float  qg = sqg[base + n + u];
                    #pragma unroll
                    for (int k = 0; k < APT; ++k) {
                        float lx = fmaxf(ax1[k], g.x);
                        float ly = fmaxf(ay1[k], g.y);
                        float rx = fminf(ax2[k], g.z);
                        float ry = fminf(ay2[k], g.w);
                        float w  = fmaxf(rx - lx, 0.f);
                        float h  = fmaxf(ry - ly, 0.f);
                        float inter = w * h;
                        cnt[k] += (inter > qa[k] + qg) ? 1 : 0;
                    }
                }
            }
            const float2* cp = reinterpret_cast<const float2*>(classes) + (size_t)b * NANCH;
            #pragma unroll
            for (int k = 0; k < APT; ++k) {
                float2 c = cp[abase + k*THREADS];
                float p  = (cnt[k] > 0) ? c.y : c.x;
                float f  = focal_f(p);
                acc += (double)(f * (1.0f + 10.0f * (float)cnt[k]));
            }
        }
        #pragma unroll
        for (int off = 32; off; off >>= 1) acc += __shfl_xor(acc, off, 64);
        if (ln == 0) sw[wv] = acc;
        __syncthreads();
        if (tid == 0) partials[bid] = sw[0] + sw[1] + sw[2] + sw[3];

    } else {
        // ==================== argmax role ====================
        int bu   = bid >> 7;             // /BPB_A
        int blkc = bid & (BPB_A - 1);
        if (bu >= *nbund) return;
        int wv = tid >> 6, ln = tid & 63;
        int abase = (blkc*4 + wv) * AC_ANCH;

        int lp = lanepk[bu*NMAX + ln];
        bool valid = lp >= 0;
        int gidx = valid ? ((lp >> 8)*NMAX + (lp & 255)) : 0;
        float4 gg = reinterpret_cast<const float4*>(gt)[gidx];
        float gx2 = gg.x + gg.z, gy2 = gg.y + gg.w;
        float gar = (gx2 - gg.x) * (gy2 - gg.y);

        // 8 independent chains; sa-form cross-mult:
        // iouA > iouB  <=>  interA*saB > interB*saA   (sa = areaA+areaB > 0)
        float bn[8], bs[8]; int bj[8];
        #pragma unroll
        for (int u = 0; u < 8; ++u) { bn[u] = -1.f; bs[u] = 1.f; bj[u] = 0; }
        const float4* ap = reinterpret_cast<const float4*>(anchors) + abase;

        // register double-buffer: compute group while next group's loads fly
        float4 va[4], vb[4];
        #pragma unroll
        for (int u = 0; u < 4; ++u) va[u] = ap[u];
        #pragma unroll
        for (int u = 0; u < 4; ++u) vb[u] = ap[4 + u];
        for (int j = 0; j < AC_ANCH; j += 8) {
            int jn = (j + 8 < AC_ANCH) ? (j + 8) : j;  // clamp: tail reload unused
            #pragma unroll
            for (int u = 0; u < 4; ++u) {
                float4 v = va[u];
                float aar = (v.z - v.x) * (v.w - v.y);
                float lx = fmaxf(v.x, gg.x), ly = fmaxf(v.y, gg.y);
                float rx = fminf(v.z, gx2),  ry = fminf(v.w, gy2);
                float w  = fmaxf(rx - lx, 0.f), h = fmaxf(ry - ly, 0.f);
                float inter = w * h;
                float sa    = aar + gar;            // > 0
                bool better = inter * bs[u] > bn[u] * sa;
                bn[u] = better ? inter : bn[u];
                bs[u] = better ? sa    : bs[u];
                bj[u] = better ? (j+u) : bj[u];
            }
            #pragma unroll
            for (int u = 0; u < 4; ++u) va[u] = ap[jn + u];
            #pragma unroll
            for (int u = 0; u < 4; ++u) {
                float4 v = vb[u];
                float aar = (v.z - v.x) * (v.w - v.y);
                float lx = fmaxf(v.x, gg.x), ly = fmaxf(v.y, gg.y);
                float rx = fminf(v.z, gx2),  ry = fminf(v.w, gy2);
                float w  = fmaxf(rx - lx, 0.f), h = fmaxf(ry - ly, 0.f);
                float inter = w * h;
                float sa    = aar + gar;
                int c = 4 + u;
                bool better = inter * bs[c] > bn[c] * sa;
                bn[c] = better ? inter     : bn[c];
                bs[c] = better ? sa        : bs[c];
                bj[c] = better ? (j+4+u)   : bj[c];
            }
            #pragma unroll
            for (int u = 0; u < 4; ++u) vb[u] = ap[jn + 4 + u];
        }
        if (valid) {
            ull best = 0;
            #pragma unroll
            for (int u = 0; u < 8; ++u) {
                float rr = bn[u] * __builtin_amdgcn_rcpf(bs[u]);  // order only
                unsigned aidx = (unsigned)(abase + bj[u]);
                ull pk = ((ull)__float_as_uint(rr) << 32)
                       | (ull)(0x7FFFFFFFu - aidx);
                best = pk > best ? pk : best;
            }
            atomicMax(&cells[(lp >> 8)*NMAX + (lp & 255)], best);
        }
    }
}

// One block, 1024 threads: sparse forced-positive correction (batch = tid>>6)
// + final reduction. Predicate expressions textually identical to the count
// role so the "old" contribution cancels exactly.
__global__ __launch_bounds__(1024) void k_tail(
    const float* __restrict__ thr_p,
    const float* __restrict__ classes,
    const float* __restrict__ anchors,
    const float* __restrict__ gt,
    const int*   __restrict__ nobj,
    const ull*   __restrict__ cells,
    const double* __restrict__ partials,
    float* __restrict__ out)
{
    int tid = threadIdx.x;
    int b = tid >> 6, n = tid & 63;
    float thr = *thr_p;
    float q   = thr / (1.0f + thr);

    __shared__ float4 sbox[NBATCH*NMAX];
    __shared__ float  sqg[NBATCH*NMAX];
    __shared__ int    sidx[NBATCH*NMAX];
    __shared__ double sdelta[NBATCH];
    __shared__ double sw[16];

    int n_obj = nobj[b];
    {
        float4 g = reinterpret_cast<const float4*>(gt)[b*NMAX + n];
        float x2 = g.x + g.z, y2 = g.y + g.w;
        sbox[tid] = make_float4(g.x, g.y, x2, y2);
        float gar = (x2 - g.x) * (y2 - g.y);
        sqg[tid]  = q * gar;
    }
    __syncthreads();

    int bi = -1; bool need = false;
    float4 av = make_float4(0.f,0.f,0.f,0.f);
    float qa = 0.f;
    if (n < n_obj) {
        ull pkv = cells[tid];
        bi = (int)(0x7FFFFFFFu - (unsigned)(pkv & 0xFFFFFFFFull));
        av = reinterpret_cast<const float4*>(anchors)[bi];
        float aar = (av.z - av.x) * (av.w - av.y);
        qa = q * aar;
        float4 g = sbox[tid];
        float lx = fmaxf(av.x, g.x), ly = fmaxf(av.y, g.y);
        float rx = fminf(av.z, g.z), ry = fminf(av.w, g.w);
        float w  = fmaxf(rx - lx, 0.f), h = fmaxf(ry - ly, 0.f);
        float inter = w * h;
        need = !(inter > qa + sqg[tid]);  // forced adds a bit only if !pos
    }
    sidx[tid] = need ? bi : -1;
    __syncthreads();

    double delta = 0.0;
    if (need) {
        bool first = true; int extra = 0;
        int base = b * NMAX;
        for (int m = 0; m < NMAX; ++m) {
            if (sidx[base + m] == bi) { if (m < n) first = false; ++extra; }
        }
        if (first) {
            int count = 0;
            for (int m = 0; m < n_obj; ++m) {
                float4 g = sbox[base + m];
                float lx = fmaxf(av.x, g.x), ly = fmaxf(av.y, g.y);
                float rx = fminf(av.z, g.z), ry = fminf(av.w, g.w);
                float w  = fmaxf(rx - lx, 0.f), h = fmaxf(ry - ly, 0.f);
                float inter = w * h;
                count += (inter > qa + sqg[base + m]) ? 1 : 0;
            }
            float2 c = reinterpret_cast<const float2*>(classes)[(size_t)b * NANCH + bi];
            float po = (count > 0) ? c.y : c.x;
            float fo = focal_f(po);
            float oldc = fo * (1.0f + 10.0f * (float)count);
            int cn = count + extra;
            float pn = (cn > 0) ? c.y : c.x;
            float fn = focal_f(pn);
            float newc = fn * (1.0f + 10.0f * (float)cn);
            delta = (double)newc - (double)oldc;
        }
    }
    #pragma unroll
    for (int off = 32; off; off >>= 1) delta += __shfl_xor(delta, off, 64);
    if (n == 0) sdelta[b] = delta;
    __syncthreads();

    // final: 1024 count partials map 1:1 to threads, plus 16 deltas
    double v = partials[tid];
    if (tid < NBATCH) v += sdelta[tid];
    #pragma unroll
    for (int off = 32; off; off >>= 1) v += __shfl_xor(v, off, 64);
    if ((tid & 63) == 0) sw[tid >> 6] = v;
    __syncthreads();
    if (tid == 0) {
        double tot = 0.0;
        #pragma unroll
        for (int i = 0; i < 16; ++i) tot += sw[i];
        double cls = tot * (0.01 / 16.0);
        out[0] = (float)cls;   // total = class + coord(0)
        out[1] = (float)cls;
        out[2] = 0.0f;
    }
}

extern "C" void kernel_launch(void* const* d_in, const int* in_sizes, int n_in,
                              void* d_out, int out_size, void* d_ws, size_t ws_size,
                              hipStream_t stream) {
    const float* thr     = (const float*)d_in[0];
    const float* classes = (const float*)d_in[1];
    const float* anchors = (const float*)d_in[2];
    const float* gt      = (const float*)d_in[3];
    const int*   nobj    = (const int*)d_in[4];
    float* out = (float*)d_out;

    char* ws = (char*)d_ws;
    ull*    cells    = (ull*)(ws + 0);
    int*    pairs    = (int*)(ws + 8192);
    int*    lanepk   = (int*)(ws + 8256);
    int*    nbund    = (int*)(ws + 12352);
    double* partials = (double*)(ws + 12416);

    k_setup<<<1, 64, 0, stream>>>(nobj, cells, pairs, lanepk, nbund);
    k_main<<<GRID_MAIN, THREADS, 0, stream>>>(thr, classes, anchors, gt, nobj,
                                              pairs, lanepk, nbund, cells, partials);
    k_tail<<<1, 1024, 0, stream>>>(thr, classes, anchors, gt, nobj, cells, partials, out);
}